// Round 1
// baseline (84.608 us; speedup 1.0000x reference)
//
#include <hip/hip_runtime.h>

// MSDeformAttn sampling-weight scatter (RankDetr), bug-compatible with the
// reference's axis-mislabeled reshape: output column q' = m/48, m=(l*8+h)*300+q.
//
// Gather-style privatization. Output (S=22223, Q=300) tiled as (level-aligned
// row tiles) x (8-wide q' groups). One block per tile: zero LDS (float4) ->
// scan the q-group's samples for the tile's level, filter by tile rows,
// LDS-atomic the 4 bilinear corners -> coalesced write-out. Output written
// exactly once, no memset needed.
//
// R1 changes vs previous best (79.7us):
//  (a) TILE-MAJOR XCD MAPPING: b = 24*g + tb (24 % 8 == 0 => XCD = tb % 8).
//      All 38 q-groups of an output tile now share one XCD, so their 32B
//      partial-row stores merge to full 128B lines in that XCD's L2
//      (tile slice ~1.3MB << 4MB L2) -> no memory-side read-modify-write
//      on the 26.7MB output (caches are cold: the harness's 256MiB poison
//      fill precedes us in the timed graph).
//  (b) LOAD-BEFORE-ZERO: scan's 3 vector loads issue before the LDS zero
//      loop; the ~900cy cold-HBM miss drains under the zeroing instead of
//      serially before the compute.
//
// Occupancy: LDS = 8*1280*4 = 40960 B exactly => 4 blocks/CU, 32 waves/CU.
// Grid 38*24 = 912 (114 hole blocks exit immediately); 798 real blocks all
// co-resident (1024 slots).
//
// Static shapes: N=1, L=6, Q=300, H=8, Lv=4, P=4; TOT=230400 samples.
// spatial: (100,167),(50,84),(25,42),(13,21); lsi = 0,16700,20900,21950.

constexpr int NQ   = 300;
constexpr int QW   = 8;                  // q'-group width
constexpr int NG   = 38;                 // ceil(300/8)
constexpr int NTILES = 21;               // 15 (L0,R=7) + 4 (L1,R=15) + 1 (L2) + 1 (L3)
constexpr int MAXC = 1280;               // cells cap: L0 7*167=1169, L1 15*84=1260, L2 1050
constexpr int BLK  = 512;
constexpr int GSTRIDE = 24;              // multiple of 8 => XCD id = tb % 8 (tile-major)

__global__ __launch_bounds__(BLK, 8)
void msda_tiled(const float4* __restrict__ loc4,  // sampling_locations as float4 (2 samples each)
                const float4* __restrict__ aw4,   // attention_weights as float4 (4 samples each)
                float*        __restrict__ out) { // (S, NQ)
    __shared__ float sm[QW * MAXC];               // 40,960 B, ql-major

    const int b  = blockIdx.x;
    const int g  = b / GSTRIDE;                   // q'-group 0..37
    const int tb = b - g * GSTRIDE;               // s-tile id (+ holes)
    if (tb >= NTILES) return;                     // uniform across block, pre-barrier: safe

    int lv, r0t, nr;
    if (tb < 15)      { lv = 0; r0t = 7  * tb;        nr = min(7,  100 - r0t); }
    else if (tb < 19) { lv = 1; r0t = 15 * (tb - 15); nr = min(15, 50  - r0t); }
    else if (tb < 20) { lv = 2; r0t = 0;              nr = 25; }
    else              { lv = 3; r0t = 0;              nr = 13; }

    const int Wlv_[4] = {167, 84, 42, 21};
    const int Hlv_[4] = {100, 50, 25, 13};
    const int lsi_[4] = {0, 16700, 20900, 21950};
    const int W    = Wlv_[lv];
    const int base = lsi_[lv];
    const int g0   = g * QW;
    const int qw   = min(QW, NQ - g0);            // 8, or 4 for the last group
    const int cells = nr * W;
    const int tid  = threadIdx.x;

    // ---- scan loads FIRST: issue the 3 vector loads, let vmcnt drain under
    // the LDS-zero loop (cold caches after the harness's 256MiB poison fill).
    const int nm  = 48 * qw;                      // 384 (192 last group)
    float4 xy01, xy23, w4;
    int ql = 0;
    if (tid < nm) {
        const int mi = tid;
        const int m  = 48 * g0 + mi;
        ql = mi / 48;                             // local q' index in [0, qw)
        const int l  = m / 2400;
        const int rem = m - l * 2400;
        const int h  = rem / 300;
        const int q  = rem - h * 300;
        const int t  = (((l * 300 + q) * 8 + h) * 4 + lv) * 4;   // p=0 base
        xy01 = loc4[(t >> 1) + 0];                // (x0,y0,x1,y1)
        xy23 = loc4[(t >> 1) + 1];                // (x2,y2,x3,y3)
        w4   = aw4[t >> 2];
    }

    // zero the used LDS rows (qw full rows), float4 stores
    {
        const int nz = qw * (MAXC / 4);
        float4* sm4 = (float4*)sm;
        for (int i = tid; i < nz; i += BLK) sm4[i] = make_float4(0.f, 0.f, 0.f, 0.f);
    }
    __syncthreads();

    // scan compute: one thread per mi; mi in [0, 48*qw). m = 48*g0 + mi.
    const int rlo = r0t, rhi = r0t + nr;
    const float fW = (float)W, fH = (float)Hlv_[lv];

    if (tid < nm) {
        float* smq = &sm[ql * MAXC];

        #pragma unroll
        for (int p = 0; p < 4; ++p) {
            const float x = (p == 0) ? xy01.x : (p == 1) ? xy01.z : (p == 2) ? xy23.x : xy23.z;
            const float y = (p == 0) ? xy01.y : (p == 1) ? xy01.w : (p == 2) ? xy23.y : xy23.w;
            const float w = (p == 0) ? w4.x   : (p == 1) ? w4.y   : (p == 2) ? w4.z   : w4.w;

            const float cf  = x * fW;
            const float rf  = y * fH;
            const float cfl = floorf(cf), rfl = floorf(rf);
            const float fc  = cf - cfl, fr = rf - rfl;
            const int c0 = (int)cfl, rr = (int)rfl;
            const int c1 = c0 + 1, r1 = rr + 1;

            const bool cv0 = (unsigned)c0 < (unsigned)W;   // 0 <= c0 < W
            const bool cv1 = (unsigned)c1 < (unsigned)W;
            const bool rv0 = (rr >= rlo) & (rr < rhi);     // in-tile (implies 0<=r<H)
            const bool rv1 = (r1 >= rlo) & (r1 < rhi);

            const float omfc = 1.0f - fc, omfr = 1.0f - fr;
            if (rv0) {
                const int ro = (rr - rlo) * W;
                if (cv0) atomicAdd(&smq[ro + c0], w * omfc * omfr);
                if (cv1) atomicAdd(&smq[ro + c1], w * fc   * omfr);
            }
            if (rv1) {
                const int ro = (r1 - rlo) * W;
                if (cv0) atomicAdd(&smq[ro + c0], w * omfc * fr);
                if (cv1) atomicAdd(&smq[ro + c1], w * fc   * fr);
            }
        }
    }
    __syncthreads();

    // write-out: s in [base + r0t*W, +cells), q' in [g0, g0+qw).
    // One float4 global store per (cell, v); LDS gathers are 2 lanes/bank (free).
    // Partial-line stores merge in this tile's XCD L2 (tile-major mapping).
    const int s0  = base + r0t * W;
    const int nq4 = qw >> 2;                      // 2 (or 1 last group)
    for (int i = tid; i < cells * nq4; i += BLK) {
        const int cell = i / nq4;
        const int v    = i - cell * nq4;
        float4 val;
        val.x = sm[(v * 4 + 0) * MAXC + cell];
        val.y = sm[(v * 4 + 1) * MAXC + cell];
        val.z = sm[(v * 4 + 2) * MAXC + cell];
        val.w = sm[(v * 4 + 3) * MAXC + cell];
        *(float4*)&out[(s0 + cell) * NQ + g0 + v * 4] = val;
    }
}

extern "C" void kernel_launch(void* const* d_in, const int* in_sizes, int n_in,
                              void* d_out, int out_size, void* d_ws, size_t ws_size,
                              hipStream_t stream) {
    const float4* loc4 = (const float4*)d_in[0];  // sampling_locations (fp32), 16B-aligned
    const float4* aw4  = (const float4*)d_in[1];  // attention_weights  (fp32), 16B-aligned
    float* out = (float*)d_out;

    msda_tiled<<<NG * GSTRIDE, BLK, 0, stream>>>(loc4, aw4, out);
}